// Round 17
// baseline (159.263 us; speedup 1.0000x reference)
//
#include <hip/hip_runtime.h>

#define BB 16
#define CC 256
#define NN 2048
#define QPRE 0.25f          // Q fp8 pre-scale
#define KPRE 0.36067376f    // K fp8 pre-scale; QPRE*KPRE = log2(e)/16

typedef __attribute__((ext_vector_type(8))) short short8;
typedef __attribute__((ext_vector_type(8))) __bf16 bf16x8;
typedef __attribute__((ext_vector_type(4))) short s16x4;
typedef __attribute__((ext_vector_type(4))) float f32x4;
typedef __attribute__((ext_vector_type(16))) float f32x16;
typedef __attribute__((ext_vector_type(4))) int int4v;
typedef __attribute__((ext_vector_type(8))) int int8v;
typedef __attribute__((ext_vector_type(2))) long l64x2;

#define DEVI static __device__ __forceinline__

struct ABArg {
  short8 v;
  __device__ operator short8() const { return v; }
  __device__ operator bf16x8() const { return __builtin_bit_cast(bf16x8, v); }
};

DEVI f32x16 mfma32(short8 a, short8 b, f32x16 c) {
  return __builtin_amdgcn_mfma_f32_32x32x16_bf16(ABArg{a}, ABArg{b}, c, 0, 0, 0);
}
// MX-scaled fp8 K=64, unit scales (E8M0 127 = 2^0): 2x rate vs non-scaled fp8
DEVI f32x16 mfma8s(int8v a, int8v b, f32x16 c) {
  return __builtin_amdgcn_mfma_scale_f32_32x32x64_f8f6f4(a, b, c, 0, 0, 0, 127, 0, 127);
}

DEVI unsigned short f2bf(float f) {
  unsigned u = __builtin_bit_cast(unsigned, f);
  u = (u + 0x7fffu + ((u >> 16) & 1u)) >> 16;
  return (unsigned short)u;
}
DEVI float bf2f(unsigned short u) {
  unsigned x = (unsigned)u << 16;
  return __builtin_bit_cast(float, x);
}
DEVI unsigned char f2fp8(float f) {
  int r = __builtin_amdgcn_cvt_pk_fp8_f32(f, f, 0, false);
  return (unsigned char)(r & 0xff);
}
// swap bits 3,4 of an index (pairs two K=16 fragments into one contiguous 16B chunk)
DEVI int psi(int c) { return (c & ~24) | ((c & 8) << 1) | ((c & 16) >> 1); }

DEVI void gl_lds16(const void* g, void* l) {
  __builtin_amdgcn_global_load_lds(
      (const __attribute__((address_space(1))) void*)g,
      (__attribute__((address_space(3))) void*)l, 16, 0, 0);
}

// stage 64 rows x 512B from src into lds, linear dest + inverse-swizzled source.
DEVI void stage64(const char* src, char* dst, int tid) {
#pragma unroll
  for (int i = 0; i < 8; i++) {
    int ch = tid + 256 * i;
    int row = ch >> 5, slot = ch & 31;
    gl_lds16(src + (size_t)row * 512 + ((slot * 16) ^ ((row & 7) << 4)), dst + ch * 16);
  }
}

// fragment read from a staged Nx512B bf16 tile (lane&31 -> row, h -> k-half)
DEVI short8 ldsfrag(const char* lds, int row, int kc, int h) {
  return *(const short8*)(lds + row * 512 + ((kc * 32 + h * 16) ^ ((row & 7) << 4)));
}

DEVI int drow(int r, int h) { return (r & 3) + 8 * (r >> 2) + 4 * h; }

DEVI int8v cat8(int4v lo, int4v hi) {
  int8v v;
  v[0] = lo[0]; v[1] = lo[1]; v[2] = lo[2]; v[3] = lo[3];
  v[4] = hi[0]; v[5] = hi[1]; v[6] = hi[2]; v[7] = hi[3];
  return v;
}

// ---------------- K0: merged prep: cast wq/wc, transpose w_out, bias, transpose x ----------------
__global__ __launch_bounds__(256) void k_prep(const float* wq, const float* wc, const float* wo,
                                              const float* b_out, const float* b_conv,
                                              const float* x, unsigned short* wq_b,
                                              unsigned short* wc_b, unsigned short* woT_b,
                                              float* biasv, unsigned short* xt) {
  __shared__ float tile[64][65];
  __shared__ unsigned short stile[64][65];
  int bx = blockIdx.x;
  if (bx < 768) {
    int i = bx * 256 + threadIdx.x;
    wq_b[i] = f2bf(wq[i]);
    if (i < CC * CC) wc_b[i] = f2bf(wc[i]);
  } else if (bx < 784) {
    int rb = bx - 768;
    int n0 = (rb & 3) * 64, c0 = (rb >> 2) * 64;
    int tcol = threadIdx.x & 63, trq = threadIdx.x >> 6;
#pragma unroll
    for (int rr = 0; rr < 16; rr++) {
      int cl = rr * 4 + trq;
      tile[cl][tcol] = wo[(size_t)(c0 + cl) * CC + n0 + tcol];
    }
    __syncthreads();
#pragma unroll
    for (int rr = 0; rr < 16; rr++) {
      int nl = rr * 4 + trq;
      woT_b[(size_t)(n0 + nl) * CC + c0 + tcol] = f2bf(tile[tcol][nl]);
    }
  } else if (bx < 848) {
    int o = (bx - 784) * 4 + (threadIdx.x >> 6);
    int lane = threadIdx.x & 63;
    f32x4 wv = *(const f32x4*)(wc + (size_t)o * CC + lane * 4);
    f32x4 bv = *(const f32x4*)(b_out + lane * 4);
    float s = wv[0] * bv[0] + wv[1] * bv[1] + wv[2] * bv[2] + wv[3] * bv[3];
#pragma unroll
    for (int d = 1; d < 64; d <<= 1) s += __shfl_xor(s, d, 64);
    if (lane == 0) biasv[o] = b_conv[o] - s;
  } else {
    // transpose x [B,C,N] f32 -> xt [B,N,C] bf16 ; 2048 tile-blocks
    int tb = bx - 848;
    int b = tb >> 7;
    int rem = tb & 127;
    int n0 = (rem & 31) * 64, c0 = (rem >> 5) * 64;
    int tcol = threadIdx.x & 63, trq = threadIdx.x >> 6;
    const float* xp = x + (size_t)b * CC * NN;
#pragma unroll
    for (int rr = 0; rr < 16; rr++) {
      int cl = rr * 4 + trq;
      stile[cl][tcol] = f2bf(xp[(size_t)(c0 + cl) * NN + n0 + tcol]);
    }
    __syncthreads();
    unsigned short* xtp = xt + (size_t)b * NN * CC;
#pragma unroll
    for (int rr = 0; rr < 16; rr++) {
      int nl = rr * 4 + trq;
      xtp[(size_t)(n0 + nl) * CC + c0 + tcol] = stile[tcol][nl];
    }
  }
}

// ---------------- K0c: wccN[o][c'] = -sum_c w_conv[o][c]*w_out[c][c'] ----------------
__global__ __launch_bounds__(256) void k_wcc(const unsigned short* wc_b,
                                             const unsigned short* woT_b, unsigned short* wccN) {
  __shared__ unsigned short WT[64 * 256];
  int o0 = blockIdx.x * 128, c0 = blockIdx.y * 64;
  int tid = threadIdx.x, lane = tid & 63, w = tid >> 6;
  int l31 = lane & 31, h = lane >> 5;
  stage64((const char*)(woT_b + (size_t)c0 * CC), (char*)WT, tid);
  int orow = o0 + w * 32 + l31;
  short8 aw[16];
  const unsigned short* Wp = wc_b + (size_t)orow * CC;
#pragma unroll
  for (int kc = 0; kc < 16; kc++) aw[kc] = *(const short8*)(Wp + kc * 16 + h * 8);
  __syncthreads();
  const char* Wl = (const char*)WT;
  f32x16 acc[2];
#pragma unroll
  for (int t = 0; t < 2; t++) {
#pragma unroll
    for (int r = 0; r < 16; r++) acc[t][r] = 0.f;
#pragma unroll
    for (int kc = 0; kc < 16; kc++)
      acc[t] = mfma32(aw[kc], ldsfrag(Wl, t * 32 + l31, kc, h), acc[t]);
  }
#pragma unroll
  for (int t = 0; t < 2; t++)
#pragma unroll
    for (int r = 0; r < 16; r++) {
      int od = o0 + w * 32 + drow(r, h);
      wccN[(size_t)od * CC + c0 + t * 32 + l31] = f2bf(-acc[t][r]);
    }
}

// ---------------- K2: QKV GEMM -> fp8 Q/K/V ----------------
__global__ __launch_bounds__(256, 2) void k_qkv(const unsigned short* xt,
                                                const unsigned short* wqkv_b, unsigned char* Qf,
                                                unsigned char* Kf, unsigned char* Vf) {
  __shared__ unsigned short XT[2][64 * 256];
  int o0 = blockIdx.x * 128;
  int tok_base = blockIdx.y * 256;
  int tid = threadIdx.x, lane = tid & 63, w = tid >> 6;
  int l31 = lane & 31, h = lane >> 5;

  short8 aw[16];
  const unsigned short* Wp = wqkv_b + (size_t)(o0 + w * 32 + l31) * CC;
#pragma unroll
  for (int kc = 0; kc < 16; kc++) aw[kc] = *(const short8*)(Wp + kc * 16 + h * 8);

  const char* Xg = (const char*)xt;
  stage64(Xg + (size_t)tok_base * 512, (char*)XT[0], tid);
  __syncthreads();

  int od_l = o0 + w * 32 + l31;
  int psiod = psi(od_l & 255);
  int psil31 = psi(l31);

  int cur = 0;
  for (int tt = 0; tt < 4; tt++) {
    if (tt < 3)
      stage64(Xg + (size_t)(tok_base + (tt + 1) * 64) * 512, (char*)XT[cur ^ 1], tid);
    const char* Xl = (const char*)XT[cur];
    f32x16 acc[2];
#pragma unroll
    for (int t = 0; t < 2; t++)
#pragma unroll
      for (int r = 0; r < 16; r++) acc[t][r] = 0.f;
    if (o0 < 512) {
#pragma unroll
      for (int kc = 0; kc < 16; kc++) {
        acc[0] = mfma32(ldsfrag(Xl, l31, kc, h), aw[kc], acc[0]);
        acc[1] = mfma32(ldsfrag(Xl, 32 + l31, kc, h), aw[kc], acc[1]);
      }
    } else {
#pragma unroll
      for (int kc = 0; kc < 16; kc++) {
        acc[0] = mfma32(aw[kc], ldsfrag(Xl, l31, kc, h), acc[0]);
        acc[1] = mfma32(aw[kc], ldsfrag(Xl, 32 + l31, kc, h), acc[1]);
      }
    }
    int tok0 = tok_base + tt * 64;
    if (o0 < 256) {
#pragma unroll
      for (int t = 0; t < 2; t++)
#pragma unroll
        for (int r = 0; r < 16; r++) {
          int token = tok0 + t * 32 + drow(r, h);
          Qf[(size_t)token * 256 + psiod] = f2fp8(acc[t][r] * QPRE);
        }
    } else if (o0 < 512) {
#pragma unroll
      for (int t = 0; t < 2; t++)
#pragma unroll
        for (int r = 0; r < 16; r++) {
          int token = tok0 + t * 32 + drow(r, h);
          Kf[(size_t)token * 256 + psiod] = f2fp8(acc[t][r]);
        }
    } else {
      int bb = tok0 >> 11;
      int nnb = tok0 & 2047;
#pragma unroll
      for (int t = 0; t < 2; t++)
#pragma unroll
        for (int r = 0; r < 16; r++) {
          int od = o0 + w * 32 + drow(r, h) - 512;
          Vf[(size_t)bb * 256 * NN + (size_t)od * NN + nnb + t * 32 + psil31] = f2fp8(acc[t][r]);
        }
    }
    __syncthreads();
    cur ^= 1;
  }
}

// ---------------- K3: flash attention, fp8, c-split: 64q blocks, 2 blocks/CU ----------------
// 512 blocks x 512 thr. Waves: g=w>>2 (j-half, 1024 j), p=(w>>1)&1 (q-strip of 32),
// chh=w&1 (c-half of 128). QK^T duplicated per c-half (cheap, MX K=64); PV only own half ->
// o[4] = 64 VGPR. LDS 80KB -> 2 blocks/CU = 16 waves/CU (4/SIMD).
__global__ __launch_bounds__(512, 2) void k_attn(const unsigned char* Qf, const unsigned char* Kf,
                                                 const unsigned char* Vf, unsigned short* AO) {
  __shared__ char SMEM[81920];
  int bid = blockIdx.x;
  int b = bid & 15;                 // same-batch blocks -> same XCD (bid%8==b%8)
  int q0 = (bid >> 4) * 64;
  int tid = threadIdx.x;
  int lane = tid & 63, w = tid >> 6;
  int g = w >> 2;                   // j-half
  int p = (w >> 1) & 1;             // q-strip
  int chh = w & 1;                  // c-half
  int gtid = tid & 255;
  int l31 = lane & 31, h = lane >> 5;

  char* G = SMEM + g * 40960;       // K: +0,+8192 ; V: +16384,+24576,+32768

  int qrow = q0 + p * 32 + l31;
  const unsigned char* Qp = Qf + (size_t)b * NN * 256 + (size_t)qrow * 256;
  int8v q32[4];
#pragma unroll
  for (int m = 0; m < 4; m++) {
    int4v lo = *(const int4v*)(Qp + m * 64 + h * 32);
    int4v hi = *(const int4v*)(Qp + m * 64 + h * 32 + 16);
    q32[m] = cat8(lo, hi);
  }

  f32x16 o[4];
#pragma unroll
  for (int i = 0; i < 4; i++)
#pragma unroll
    for (int r = 0; r < 16; r++) o[i][r] = 0.f;
  float lsum = 0.f;

  const unsigned char* Kg8 = Kf + (size_t)b * NN * 256;
  const unsigned char* Vg8 = Vf + (size_t)b * 256 * NN;
  int jbase = g * 1024;
  int swzk = (l31 & 7) << 4;
  int swzv = ((l31 >> 2) & 1) << 4;

  auto stage_k = [&](char* dst, int j0) {
#pragma unroll
    for (int i = 0; i < 2; i++) {
      int ch = gtid + 256 * i;
      int row = ch >> 4, slot = ch & 15;
      gl_lds16(Kg8 + (size_t)(j0 + row) * 256 + ((slot * 16) ^ ((row & 7) << 4)), dst + ch * 16);
    }
  };
  auto stage_v = [&](char* dst, int j0) {
#pragma unroll
    for (int i = 0; i < 2; i++) {
      int ch = gtid + 256 * i;
      int row = ch >> 1, slot = ch & 1;
      gl_lds16(Vg8 + (size_t)row * 2048 + j0 + ((slot * 16) ^ (((row >> 2) & 1) << 4)),
               dst + ch * 16);
    }
  };

  stage_k(G, jbase);
  stage_v(G + 16384, jbase);
  __syncthreads();

  int ps0 = 0, ps1 = 0, ps2 = 0, ps3 = 0;   // saved P pack from even iter
  for (int t = 0; t < 32; t++) {
    char* Kc = G + (t & 1) * 8192;
    if (t < 31) {
      int j0n = jbase + (t + 1) * 32;
      stage_k(G + ((t + 1) & 1) * 8192, j0n);
      stage_v(G + 16384 + ((t + 1) % 3) * 8192, j0n);
    }

    // QK^T (swapped, MX-scaled K=64): 4 instructions cover K=256
    f32x16 s;
#pragma unroll
    for (int r = 0; r < 16; r++) s[r] = 0.f;
    __builtin_amdgcn_s_setprio(1);
#pragma unroll
    for (int m = 0; m < 4; m++) {
      int base = l31 * 256;
      int4v lo = *(const int4v*)(Kc + base + ((m * 64 + h * 32) ^ swzk));
      int4v hi = *(const int4v*)(Kc + base + ((m * 64 + h * 32 + 16) ^ swzk));
      s = mfma8s(cat8(lo, hi), q32[m], s);
    }
    __builtin_amdgcn_s_setprio(0);

    // softmax (log2 domain; scale pre-folded into Q,K)
    float pv[16];
#pragma unroll
    for (int r = 0; r < 16; r++) pv[r] = __builtin_amdgcn_exp2f(s[r]);
    {
      float a0 = (pv[0] + pv[1]) + (pv[2] + pv[3]);
      float a1 = (pv[4] + pv[5]) + (pv[6] + pv[7]);
      float a2 = (pv[8] + pv[9]) + (pv[10] + pv[11]);
      float a3 = (pv[12] + pv[13]) + (pv[14] + pv[15]);
      lsum += (a0 + a1) + (a2 + a3);
    }

    int C0 = __builtin_amdgcn_cvt_pk_fp8_f32(pv[0], pv[1], 0, false);
    C0 = __builtin_amdgcn_cvt_pk_fp8_f32(pv[2], pv[3], C0, true);
    int C1 = __builtin_amdgcn_cvt_pk_fp8_f32(pv[4], pv[5], 0, false);
    C1 = __builtin_amdgcn_cvt_pk_fp8_f32(pv[6], pv[7], C1, true);
    int C2 = __builtin_amdgcn_cvt_pk_fp8_f32(pv[8], pv[9], 0, false);
    C2 = __builtin_amdgcn_cvt_pk_fp8_f32(pv[10], pv[11], C2, true);
    int C3 = __builtin_amdgcn_cvt_pk_fp8_f32(pv[12], pv[13], 0, false);
    C3 = __builtin_amdgcn_cvt_pk_fp8_f32(pv[14], pv[15], C3, true);

    if ((t & 1) == 0) {
      ps0 = C0; ps1 = C1; ps2 = C2; ps3 = C3;
    } else {
      // build K=64 A-frag: low lanes (h=0) -> tile t-1 (all 32 j), high -> tile t
      int x0 = ps0, y0 = C0;
      asm volatile("v_permlane32_swap_b32 %0, %1" : "+v"(x0), "+v"(y0));
      int x1 = ps1, y1 = C1;
      asm volatile("v_permlane32_swap_b32 %0, %1" : "+v"(x1), "+v"(y1));
      int x2 = ps2, y2 = C2;
      asm volatile("v_permlane32_swap_b32 %0, %1" : "+v"(x2), "+v"(y2));
      int x3 = ps3, y3 = C3;
      asm volatile("v_permlane32_swap_b32 %0, %1" : "+v"(x3), "+v"(y3));
      int8v pa;
      pa[0] = x0; pa[1] = y0;   // bytes 0-7   -> j 0-7   (psi)
      pa[2] = x2; pa[3] = y2;   // bytes 8-15  -> j 16-23
      pa[4] = x1; pa[5] = y1;   // bytes 16-23 -> j 8-15
      pa[6] = x3; pa[7] = y3;   // bytes 24-31 -> j 24-31
      // PV over (t-1, t) for own c-half: lane-half h reads its tile's V buffer
      char* Vh = G + 16384 + ((t - 1 + h) % 3) * 8192;
      __builtin_amdgcn_s_setprio(1);
#pragma unroll
      for (int ct = 0; ct < 4; ct++) {
        int rowb = (((chh * 4 + ct) * 32 + l31)) * 32;
        int4v lo = *(const int4v*)(Vh + rowb + (0 ^ swzv));
        int4v hi = *(const int4v*)(Vh + rowb + (16 ^ swzv));
        o[ct] = mfma8s(pa, cat8(lo, hi), o[ct]);
      }
      __builtin_amdgcn_s_setprio(0);
    }

    __syncthreads();
  }

  // complete q-row sums (cross-half), then combine j-halves (partner = w^4)
  lsum += __shfl_xor(lsum, 32, 64);
  float* Lx = (float*)SMEM;   // 8 waves x 32 floats = 1 KB
  if (h == 0) Lx[w * 32 + l31] = lsum;
  __syncthreads();
  float ltot = lsum + Lx[((w ^ 4) * 32) + l31];
  float linv[16];
#pragma unroll
  for (int r = 0; r < 16; r++) linv[r] = 1.f / __shfl(ltot, drow(r, h), 64);
  __syncthreads();

  // O-combine across j-halves: g1 writes o[4] (4 regions x 16KB = 64KB), g0 sums+stores
  unsigned short* AOp = AO + (size_t)b * NN * CC;
  char* Rb = SMEM + (w & 3) * 16384;
  if (g == 1) {
#pragma unroll
    for (int ct = 0; ct < 4; ct++)
#pragma unroll
      for (int k = 0; k < 4; k++) {
        f32x4 v = {o[ct][4 * k], o[ct][4 * k + 1], o[ct][4 * k + 2], o[ct][4 * k + 3]};
        *(f32x4*)(Rb + ((ct * 4 + k) * 64 + lane) * 16) = v;
      }
  }
  __syncthreads();
  if (g == 0) {
#pragma unroll
    for (int ct = 0; ct < 4; ct++)
#pragma unroll
      for (int k = 0; k < 4; k++) {
        f32x4 qv = *(const f32x4*)(Rb + ((ct * 4 + k) * 64 + lane) * 16);
#pragma unroll
        for (int j = 0; j < 4; j++) {
          int r = 4 * k + j;
          float v = (o[ct][r] + qv[j]) * linv[r];
          AOp[(size_t)(q0 + p * 32 + drow(r, h)) * CC + (chh * 4 + ct) * 32 + l31] = f2bf(v);
        }
      }
  }
}

// ---------------- K4: fused proj+conv + BN stats (swapped: lane-axis = channel) ----------------
__global__ __launch_bounds__(256, 1) void k_fused(const unsigned short* xt,
                                                  const unsigned short* AO,
                                                  const unsigned short* wc_b,
                                                  const unsigned short* wccN, const float* biasv,
                                                  unsigned short* yT, float* psum, float* psq) {
  __shared__ unsigned short XT[2][64 * 256], AL[2][64 * 256];   // 128 KB
  int o0 = blockIdx.x * 128;
  int tok_base = blockIdx.y * 256;
  int tid = threadIdx.x, lane = tid & 63, w = tid >> 6;
  int l31 = lane & 31, h = lane >> 5;
  int od = o0 + w * 32 + l31;

  short8 aw[32];
  const unsigned short* Wp1 = wc_b + (size_t)od * CC;
  const unsigned short* Wp2 = wccN + (size_t)od * CC;
#pragma unroll
  for (int kc = 0; kc < 16; kc++) {
    aw[kc] = *(const short8*)(Wp1 + kc * 16 + h * 8);
    aw[16 + kc] = *(const short8*)(Wp2 + kc * 16 + h * 8);
  }
  float bias_l = biasv[od];
  float sacc = 0.f, qacc = 0.f;

  const char* Xg = (const char*)xt;
  const char* Ag = (const char*)AO;
  stage64(Xg + (size_t)tok_base * 512, (char*)XT[0], tid);
  stage64(Ag + (size_t)tok_base * 512, (char*)AL[0], tid);
  __syncthreads();

  int cur = 0;
  for (int tt = 0; tt < 4; tt++) {
    if (tt < 3) {
      stage64(Xg + (size_t)(tok_base + (tt + 1) * 64) * 512, (char*)XT[cur ^ 1], tid);
      stage64(Ag + (size_t)(tok_base + (tt + 1) * 64) * 512, (char*)AL[cur ^ 1], tid);
    }
    const char* Xl = (const char*)XT[cur];
    const char* Al = (const char*)AL[cur];
    f32x16 acc[2];
#pragma unroll
    for (int t = 0; t < 2; t++)
#pragma unroll
      for (int r = 0; r < 16; r++) acc[t][r] = 0.f;
#pragma unroll
    for (int kc = 0; kc < 16; kc++) {
      acc[0] = mfma32(ldsfrag(Xl, l31, kc, h), aw[kc], acc[0]);
      acc[1] = mfma32(ldsfrag(Xl, 32 + l31, kc, h), aw[kc], acc[1]);
    }
#pragma unroll
    for (int kc = 0; kc < 16; kc++) {
      acc[0] = mfma32(ldsfrag(Al, l31, kc, h), aw[16 + kc], acc[0]);
      acc[1] = mfma32(ldsfrag(Al, 32 + l31, kc, h), aw[16 + kc], acc[1]);
    }
    int tok0 = tok_base + tt * 64;
#pragma unroll
    for (int t = 0; t < 2; t++)
#pragma unroll
      for (int r = 0; r < 16; r++) {
        float v = acc[t][r] + bias_l;
        sacc += v;
        qacc += v * v;
        int token = tok0 + t * 32 + drow(r, h);
        yT[(size_t)token * CC + od] = f2bf(v);
      }
    __syncthreads();
    cur ^= 1;
  }

  sacc += __shfl_xor(sacc, 32, 64);
  qacc += __shfl_xor(qacc, 32, 64);
  if (h == 0) {
    psum[blockIdx.y * 256 + od] = sacc;
    psq[blockIdx.y * 256 + od] = qacc;
  }
}

// ---------------- K5: finalize scale/shift (4-way parallel over 128 rows) ----------------
__global__ __launch_bounds__(1024) void k_stats2(const float* psum, const float* psq,
                                                 const float* gamma, const float* beta,
                                                 float* scale, float* shift) {
  __shared__ float S4[4][256], Q4[4][256];
  int o = threadIdx.x & 255, part = threadIdx.x >> 8;
  float S = 0.f, Q = 0.f;
  for (int b = part * 32; b < part * 32 + 32; b++) {
    S += psum[b * 256 + o];
    Q += psq[b * 256 + o];
  }
  S4[part][o] = S;
  Q4[part][o] = Q;
  __syncthreads();
  if (part == 0) {
    S = S4[0][o] + S4[1][o] + S4[2][o] + S4[3][o];
    Q = Q4[0][o] + Q4[1][o] + Q4[2][o] + Q4[3][o];
    const float inv = 1.f / (BB * NN);
    float mean = S * inv;
    float var = Q * inv - mean * mean;
    float rstd = rsqrtf(var + 1e-5f);
    float sc = gamma[o] * rstd;
    scale[o] = sc;
    shift[o] = beta[o] - mean * sc;
  }
}

// ---------------- K6: transpose yT + BN + relu + residual ----------------
__global__ __launch_bounds__(256) void k_final(const unsigned short* yT, const float* x,
                                               const float* scale, const float* shift, float* out) {
  __shared__ float tile[64][65];
  int n0 = blockIdx.x * 64, c0 = blockIdx.y * 64, b = blockIdx.z;
  int tid = threadIdx.x;
#pragma unroll
  for (int it = 0; it < 2; it++) {
    int rowl = (tid >> 3) + it * 32, slot = tid & 7;
    short8 v = *(const short8*)(yT + (size_t)(b * NN + n0 + rowl) * CC + c0 + slot * 8);
#pragma unroll
    for (int j = 0; j < 8; j++) tile[rowl][slot * 8 + j] = bf2f((unsigned short)v[j]);
  }
  __syncthreads();
  int nl = tid & 63, cg = tid >> 6;
  size_t xb = (size_t)b * CC * NN;
#pragma unroll
  for (int i = 0; i < 16; i++) {
    int cl = cg * 16 + i;
    int c = c0 + cl;
    float v = tile[nl][cl] * scale[c] + shift[c];
    size_t idx = xb + (size_t)c * NN + n0 + nl;
    out[idx] = x[idx] + fmaxf(v, 0.f);
  }
}

extern "C" void kernel_launch(void* const* d_in, const int* in_sizes, int n_in,
                              void* d_out, int out_size, void* d_ws, size_t ws_size,
                              hipStream_t stream) {
  const float* x      = (const float*)d_in[0];
  const float* w_qkv  = (const float*)d_in[1];
  const float* w_out  = (const float*)d_in[2];
  const float* b_out  = (const float*)d_in[3];
  const float* w_conv = (const float*)d_in[4];
  const float* b_conv = (const float*)d_in[5];
  const float* gamma  = (const float*)d_in[6];
  const float* beta   = (const float*)d_in[7];
  float* out = (float*)d_out;

  char* ws = (char*)d_ws;
  size_t off = 0;
  auto take = [&](size_t bytes) -> char* {
    char* p = ws + off;
    off += (bytes + 255) & ~(size_t)255;
    return p;
  };
  const size_t BNC  = (size_t)BB * NN * CC;
  unsigned char* Qf  = (unsigned char*)take(BNC);   // fp8; Qf+Kf reused as yT after attn
  unsigned char* Kf  = (unsigned char*)take(BNC);
  unsigned char* Vf  = (unsigned char*)take(BNC);
  unsigned short* xt = (unsigned short*)take(BNC * 2);
  unsigned short* AO = (unsigned short*)take(BNC * 2);
  unsigned short* wq_b = (unsigned short*)take((size_t)3 * CC * CC * 2);
  unsigned short* wc_b = (unsigned short*)take((size_t)CC * CC * 2);
  unsigned short* woT_b= (unsigned short*)take((size_t)CC * CC * 2);
  unsigned short* wccN = (unsigned short*)take((size_t)CC * CC * 2);
  float* biasv = (float*)take(CC * 4);
  float* psum  = (float*)take(128 * CC * 4);
  float* psq   = (float*)take(128 * CC * 4);
  float* scale = (float*)take(CC * 4);
  float* shift = (float*)take(CC * 4);
  unsigned short* yT = (unsigned short*)Qf;   // Qf+Kf region (16 MB) dead after k_attn

  k_prep<<<2896, 256, 0, stream>>>(w_qkv, w_conv, w_out, b_out, b_conv, x, wq_b, wc_b, woT_b,
                                   biasv, xt);
  k_wcc<<<dim3(2, 4), 256, 0, stream>>>(wc_b, woT_b, wccN);
  k_qkv<<<dim3(6, 128), 256, 0, stream>>>(xt, wq_b, Qf, Kf, Vf);
  k_attn<<<512, 512, 0, stream>>>(Qf, Kf, Vf, AO);
  k_fused<<<dim3(2, 128), 256, 0, stream>>>(xt, AO, wc_b, wccN, biasv, yT, psum, psq);
  k_stats2<<<1, 1024, 0, stream>>>(psum, psq, gamma, beta, scale, shift);
  k_final<<<dim3(32, 4, BB), 256, 0, stream>>>(yT, x, scale, shift, out);
}

// Round 18
// 131.916 us; speedup vs baseline: 1.2073x; 1.2073x over previous
//
#include <hip/hip_runtime.h>

#define BB 16
#define CC 256
#define NN 2048
#define QPRE 0.25f          // Q fp8 pre-scale
#define KPRE 0.36067376f    // K fp8 pre-scale; QPRE*KPRE = log2(e)/16

typedef __attribute__((ext_vector_type(8))) short short8;
typedef __attribute__((ext_vector_type(8))) __bf16 bf16x8;
typedef __attribute__((ext_vector_type(4))) short s16x4;
typedef __attribute__((ext_vector_type(4))) float f32x4;
typedef __attribute__((ext_vector_type(16))) float f32x16;
typedef __attribute__((ext_vector_type(4))) int int4v;
typedef __attribute__((ext_vector_type(8))) int int8v;
typedef __attribute__((ext_vector_type(2))) long l64x2;

#define DEVI static __device__ __forceinline__

struct ABArg {
  short8 v;
  __device__ operator short8() const { return v; }
  __device__ operator bf16x8() const { return __builtin_bit_cast(bf16x8, v); }
};

DEVI f32x16 mfma32(short8 a, short8 b, f32x16 c) {
  return __builtin_amdgcn_mfma_f32_32x32x16_bf16(ABArg{a}, ABArg{b}, c, 0, 0, 0);
}
// MX-scaled fp8 K=64, unit scales (E8M0 127 = 2^0): 2x rate vs non-scaled fp8
DEVI f32x16 mfma8s(int8v a, int8v b, f32x16 c) {
  return __builtin_amdgcn_mfma_scale_f32_32x32x64_f8f6f4(a, b, c, 0, 0, 0, 127, 0, 127);
}

DEVI unsigned short f2bf(float f) {
  unsigned u = __builtin_bit_cast(unsigned, f);
  u = (u + 0x7fffu + ((u >> 16) & 1u)) >> 16;
  return (unsigned short)u;
}
DEVI float bf2f(unsigned short u) {
  unsigned x = (unsigned)u << 16;
  return __builtin_bit_cast(float, x);
}
DEVI unsigned char f2fp8(float f) {
  int r = __builtin_amdgcn_cvt_pk_fp8_f32(f, f, 0, false);
  return (unsigned char)(r & 0xff);
}
// swap bits 3,4 of an index (pairs two K=16 fragments into one contiguous 16B chunk)
DEVI int psi(int c) { return (c & ~24) | ((c & 8) << 1) | ((c & 16) >> 1); }

DEVI void gl_lds16(const void* g, void* l) {
  __builtin_amdgcn_global_load_lds(
      (const __attribute__((address_space(1))) void*)g,
      (__attribute__((address_space(3))) void*)l, 16, 0, 0);
}

// stage 64 rows x 512B from src into lds, linear dest + inverse-swizzled source.
DEVI void stage64(const char* src, char* dst, int tid) {
#pragma unroll
  for (int i = 0; i < 8; i++) {
    int ch = tid + 256 * i;
    int row = ch >> 5, slot = ch & 31;
    gl_lds16(src + (size_t)row * 512 + ((slot * 16) ^ ((row & 7) << 4)), dst + ch * 16);
  }
}

// fragment read from a staged Nx512B bf16 tile (lane&31 -> row, h -> k-half)
DEVI short8 ldsfrag(const char* lds, int row, int kc, int h) {
  return *(const short8*)(lds + row * 512 + ((kc * 32 + h * 16) ^ ((row & 7) << 4)));
}

DEVI int drow(int r, int h) { return (r & 3) + 8 * (r >> 2) + 4 * h; }

DEVI int8v cat8(int4v lo, int4v hi) {
  int8v v;
  v[0] = lo[0]; v[1] = lo[1]; v[2] = lo[2]; v[3] = lo[3];
  v[4] = hi[0]; v[5] = hi[1]; v[6] = hi[2]; v[7] = hi[3];
  return v;
}

// ---------------- K0: merged prep: cast wq/wc, transpose w_out, bias, transpose x ----------------
__global__ __launch_bounds__(256) void k_prep(const float* wq, const float* wc, const float* wo,
                                              const float* b_out, const float* b_conv,
                                              const float* x, unsigned short* wq_b,
                                              unsigned short* wc_b, unsigned short* woT_b,
                                              float* biasv, unsigned short* xt) {
  __shared__ float tile[64][65];
  __shared__ unsigned short stile[64][65];
  int bx = blockIdx.x;
  if (bx < 768) {
    int i = bx * 256 + threadIdx.x;
    wq_b[i] = f2bf(wq[i]);
    if (i < CC * CC) wc_b[i] = f2bf(wc[i]);
  } else if (bx < 784) {
    int rb = bx - 768;
    int n0 = (rb & 3) * 64, c0 = (rb >> 2) * 64;
    int tcol = threadIdx.x & 63, trq = threadIdx.x >> 6;
#pragma unroll
    for (int rr = 0; rr < 16; rr++) {
      int cl = rr * 4 + trq;
      tile[cl][tcol] = wo[(size_t)(c0 + cl) * CC + n0 + tcol];
    }
    __syncthreads();
#pragma unroll
    for (int rr = 0; rr < 16; rr++) {
      int nl = rr * 4 + trq;
      woT_b[(size_t)(n0 + nl) * CC + c0 + tcol] = f2bf(tile[tcol][nl]);
    }
  } else if (bx < 848) {
    int o = (bx - 784) * 4 + (threadIdx.x >> 6);
    int lane = threadIdx.x & 63;
    f32x4 wv = *(const f32x4*)(wc + (size_t)o * CC + lane * 4);
    f32x4 bv = *(const f32x4*)(b_out + lane * 4);
    float s = wv[0] * bv[0] + wv[1] * bv[1] + wv[2] * bv[2] + wv[3] * bv[3];
#pragma unroll
    for (int d = 1; d < 64; d <<= 1) s += __shfl_xor(s, d, 64);
    if (lane == 0) biasv[o] = b_conv[o] - s;
  } else {
    // transpose x [B,C,N] f32 -> xt [B,N,C] bf16 ; 2048 tile-blocks
    int tb = bx - 848;
    int b = tb >> 7;
    int rem = tb & 127;
    int n0 = (rem & 31) * 64, c0 = (rem >> 5) * 64;
    int tcol = threadIdx.x & 63, trq = threadIdx.x >> 6;
    const float* xp = x + (size_t)b * CC * NN;
#pragma unroll
    for (int rr = 0; rr < 16; rr++) {
      int cl = rr * 4 + trq;
      stile[cl][tcol] = f2bf(xp[(size_t)(c0 + cl) * NN + n0 + tcol]);
    }
    __syncthreads();
    unsigned short* xtp = xt + (size_t)b * NN * CC;
#pragma unroll
    for (int rr = 0; rr < 16; rr++) {
      int nl = rr * 4 + trq;
      xtp[(size_t)(n0 + nl) * CC + c0 + tcol] = stile[tcol][nl];
    }
  }
}

// ---------------- K0c: wccN[o][c'] = -sum_c w_conv[o][c]*w_out[c][c'] ----------------
__global__ __launch_bounds__(256) void k_wcc(const unsigned short* wc_b,
                                             const unsigned short* woT_b, unsigned short* wccN) {
  __shared__ unsigned short WT[64 * 256];
  int o0 = blockIdx.x * 128, c0 = blockIdx.y * 64;
  int tid = threadIdx.x, lane = tid & 63, w = tid >> 6;
  int l31 = lane & 31, h = lane >> 5;
  stage64((const char*)(woT_b + (size_t)c0 * CC), (char*)WT, tid);
  int orow = o0 + w * 32 + l31;
  short8 aw[16];
  const unsigned short* Wp = wc_b + (size_t)orow * CC;
#pragma unroll
  for (int kc = 0; kc < 16; kc++) aw[kc] = *(const short8*)(Wp + kc * 16 + h * 8);
  __syncthreads();
  const char* Wl = (const char*)WT;
  f32x16 acc[2];
#pragma unroll
  for (int t = 0; t < 2; t++) {
#pragma unroll
    for (int r = 0; r < 16; r++) acc[t][r] = 0.f;
#pragma unroll
    for (int kc = 0; kc < 16; kc++)
      acc[t] = mfma32(aw[kc], ldsfrag(Wl, t * 32 + l31, kc, h), acc[t]);
  }
#pragma unroll
  for (int t = 0; t < 2; t++)
#pragma unroll
    for (int r = 0; r < 16; r++) {
      int od = o0 + w * 32 + drow(r, h);
      wccN[(size_t)od * CC + c0 + t * 32 + l31] = f2bf(-acc[t][r]);
    }
}

// ---------------- K2: QKV GEMM -> fp8 Q/K/V ----------------
// Q/K blocks use swapped operand order (A=xt, B=weights) so lane-axis = channel ->
// fp8 stores land in one 32B sector per instruction. V keeps lane-axis = token.
__global__ __launch_bounds__(256, 2) void k_qkv(const unsigned short* xt,
                                                const unsigned short* wqkv_b, unsigned char* Qf,
                                                unsigned char* Kf, unsigned char* Vf) {
  __shared__ unsigned short XT[2][64 * 256];
  int o0 = blockIdx.x * 128;
  int tok_base = blockIdx.y * 256;
  int tid = threadIdx.x, lane = tid & 63, w = tid >> 6;
  int l31 = lane & 31, h = lane >> 5;

  short8 aw[16];
  const unsigned short* Wp = wqkv_b + (size_t)(o0 + w * 32 + l31) * CC;
#pragma unroll
  for (int kc = 0; kc < 16; kc++) aw[kc] = *(const short8*)(Wp + kc * 16 + h * 8);

  const char* Xg = (const char*)xt;
  stage64(Xg + (size_t)tok_base * 512, (char*)XT[0], tid);
  __syncthreads();

  int od_l = o0 + w * 32 + l31;       // lane-axis channel (swapped path)
  int psiod = psi(od_l & 255);
  int psil31 = psi(l31);              // V path: psi within 32-token group

  int cur = 0;
  for (int tt = 0; tt < 4; tt++) {
    if (tt < 3)
      stage64(Xg + (size_t)(tok_base + (tt + 1) * 64) * 512, (char*)XT[cur ^ 1], tid);
    const char* Xl = (const char*)XT[cur];
    f32x16 acc[2];
#pragma unroll
    for (int t = 0; t < 2; t++)
#pragma unroll
      for (int r = 0; r < 16; r++) acc[t][r] = 0.f;
    if (o0 < 512) {
      // swapped: D rows = tokens (regs), cols = od (lane)
#pragma unroll
      for (int kc = 0; kc < 16; kc++) {
        acc[0] = mfma32(ldsfrag(Xl, l31, kc, h), aw[kc], acc[0]);
        acc[1] = mfma32(ldsfrag(Xl, 32 + l31, kc, h), aw[kc], acc[1]);
      }
    } else {
#pragma unroll
      for (int kc = 0; kc < 16; kc++) {
        acc[0] = mfma32(aw[kc], ldsfrag(Xl, l31, kc, h), acc[0]);
        acc[1] = mfma32(aw[kc], ldsfrag(Xl, 32 + l31, kc, h), acc[1]);
      }
    }
    int tok0 = tok_base + tt * 64;
    if (o0 < 256) {
#pragma unroll
      for (int t = 0; t < 2; t++)
#pragma unroll
        for (int r = 0; r < 16; r++) {
          int token = tok0 + t * 32 + drow(r, h);
          Qf[(size_t)token * 256 + psiod] = f2fp8(acc[t][r] * QPRE);
        }
    } else if (o0 < 512) {
#pragma unroll
      for (int t = 0; t < 2; t++)
#pragma unroll
        for (int r = 0; r < 16; r++) {
          int token = tok0 + t * 32 + drow(r, h);
          Kf[(size_t)token * 256 + psiod] = f2fp8(acc[t][r]);
        }
    } else {
      int bb = tok0 >> 11;
      int nnb = tok0 & 2047;
#pragma unroll
      for (int t = 0; t < 2; t++)
#pragma unroll
        for (int r = 0; r < 16; r++) {
          int od = o0 + w * 32 + drow(r, h) - 512;
          Vf[(size_t)bb * 256 * NN + (size_t)od * NN + nnb + t * 32 + psil31] = f2fp8(acc[t][r]);
        }
    }
    __syncthreads();
    cur ^= 1;
  }
}

// ---------------- K3: flash attention, fp8, 8 waves (4 q-strips x 2 j-groups) ----------------
// 512 threads; launch_bounds(512,2): 2 blocks/CU (LDS-limited at 80KB each), VGPR cap 128.
__global__ __launch_bounds__(512, 2) void k_attn(const unsigned char* Qf, const unsigned char* Kf,
                                                 const unsigned char* Vf, unsigned short* AO) {
  __shared__ char SMEM[81920];
  int bid = blockIdx.x;
  int b = bid & 15;                 // same-batch blocks -> same XCD (bid%8==b%8)
  int q0 = (bid >> 4) * 128;
  int tid = threadIdx.x;
  int lane = tid & 63, w = tid >> 6;
  int g = w >> 2, p = w & 3;
  int gtid = tid & 255;
  int l31 = lane & 31, h = lane >> 5;

  char* G = SMEM + g * 40960;       // K: +0,+8192 ; V: +16384,+24576,+32768

  // Q chunks for scaled QK: 32B per lane per chunk (k = 64-wide window, half per h)
  int qrow = q0 + p * 32 + l31;
  const unsigned char* Qp = Qf + (size_t)b * NN * 256 + (size_t)qrow * 256;
  int8v q32[4];
#pragma unroll
  for (int m = 0; m < 4; m++) {
    int4v lo = *(const int4v*)(Qp + m * 64 + h * 32);
    int4v hi = *(const int4v*)(Qp + m * 64 + h * 32 + 16);
    q32[m] = cat8(lo, hi);
  }

  f32x16 o[8];
#pragma unroll
  for (int i = 0; i < 8; i++)
#pragma unroll
    for (int r = 0; r < 16; r++) o[i][r] = 0.f;
  float lsum = 0.f;

  const unsigned char* Kg8 = Kf + (size_t)b * NN * 256;
  const unsigned char* Vg8 = Vf + (size_t)b * 256 * NN;
  int jbase = g * 1024;
  int swzk = (l31 & 7) << 4;
  int swzv = ((l31 >> 2) & 1) << 4;

  auto stage_k = [&](char* dst, int j0) {
#pragma unroll
    for (int i = 0; i < 2; i++) {
      int ch = gtid + 256 * i;
      int row = ch >> 4, slot = ch & 15;
      gl_lds16(Kg8 + (size_t)(j0 + row) * 256 + ((slot * 16) ^ ((row & 7) << 4)), dst + ch * 16);
    }
  };
  auto stage_v = [&](char* dst, int j0) {
#pragma unroll
    for (int i = 0; i < 2; i++) {
      int ch = gtid + 256 * i;
      int row = ch >> 1, slot = ch & 1;
      gl_lds16(Vg8 + (size_t)row * 2048 + j0 + ((slot * 16) ^ (((row >> 2) & 1) << 4)),
               dst + ch * 16);
    }
  };

  stage_k(G, jbase);
  stage_v(G + 16384, jbase);
  __syncthreads();

  int ps0 = 0, ps1 = 0, ps2 = 0, ps3 = 0;   // saved P pack from even iter
  for (int t = 0; t < 32; t++) {
    char* Kc = G + (t & 1) * 8192;
    if (t < 31) {
      int j0n = jbase + (t + 1) * 32;
      stage_k(G + ((t + 1) & 1) * 8192, j0n);
      stage_v(G + 16384 + ((t + 1) % 3) * 8192, j0n);
    }

    // QK^T (swapped, MX-scaled K=64): 4 instructions cover K=256
    f32x16 s;
#pragma unroll
    for (int r = 0; r < 16; r++) s[r] = 0.f;
    __builtin_amdgcn_s_setprio(1);
#pragma unroll
    for (int m = 0; m < 4; m++) {
      int base = l31 * 256;
      int4v lo = *(const int4v*)(Kc + base + ((m * 64 + h * 32) ^ swzk));
      int4v hi = *(const int4v*)(Kc + base + ((m * 64 + h * 32 + 16) ^ swzk));
      s = mfma8s(cat8(lo, hi), q32[m], s);
    }
    __builtin_amdgcn_s_setprio(0);

    // softmax (log2 domain; scale pre-folded into Q,K); lsum kept half-summed
    float pv[16];
#pragma unroll
    for (int r = 0; r < 16; r++) pv[r] = __builtin_amdgcn_exp2f(s[r]);
    // balanced-tree row-sum (4-deep instead of 16-deep dependent chain)
    {
      float a0 = (pv[0] + pv[1]) + (pv[2] + pv[3]);
      float a1 = (pv[4] + pv[5]) + (pv[6] + pv[7]);
      float a2 = (pv[8] + pv[9]) + (pv[10] + pv[11]);
      float a3 = (pv[12] + pv[13]) + (pv[14] + pv[15]);
      lsum += (a0 + a1) + (a2 + a3);
    }

    int C0 = __builtin_amdgcn_cvt_pk_fp8_f32(pv[0], pv[1], 0, false);
    C0 = __builtin_amdgcn_cvt_pk_fp8_f32(pv[2], pv[3], C0, true);
    int C1 = __builtin_amdgcn_cvt_pk_fp8_f32(pv[4], pv[5], 0, false);
    C1 = __builtin_amdgcn_cvt_pk_fp8_f32(pv[6], pv[7], C1, true);
    int C2 = __builtin_amdgcn_cvt_pk_fp8_f32(pv[8], pv[9], 0, false);
    C2 = __builtin_amdgcn_cvt_pk_fp8_f32(pv[10], pv[11], C2, true);
    int C3 = __builtin_amdgcn_cvt_pk_fp8_f32(pv[12], pv[13], 0, false);
    C3 = __builtin_amdgcn_cvt_pk_fp8_f32(pv[14], pv[15], C3, true);

    if ((t & 1) == 0) {
      ps0 = C0; ps1 = C1; ps2 = C2; ps3 = C3;
    } else {
      // build K=64 A-frag: low lanes (h=0) -> tile t-1 (all 32 j), high -> tile t
      int x0 = ps0, y0 = C0;
      asm volatile("v_permlane32_swap_b32 %0, %1" : "+v"(x0), "+v"(y0));
      int x1 = ps1, y1 = C1;
      asm volatile("v_permlane32_swap_b32 %0, %1" : "+v"(x1), "+v"(y1));
      int x2 = ps2, y2 = C2;
      asm volatile("v_permlane32_swap_b32 %0, %1" : "+v"(x2), "+v"(y2));
      int x3 = ps3, y3 = C3;
      asm volatile("v_permlane32_swap_b32 %0, %1" : "+v"(x3), "+v"(y3));
      int8v pa;
      pa[0] = x0; pa[1] = y0;   // bytes 0-7   -> j 0-7   (psi)
      pa[2] = x2; pa[3] = y2;   // bytes 8-15  -> j 16-23
      pa[4] = x1; pa[5] = y1;   // bytes 16-23 -> j 8-15
      pa[6] = x3; pa[7] = y3;   // bytes 24-31 -> j 24-31
      // PV over (t-1, t): lane-half h reads its tile's V buffer
      char* Vh = G + 16384 + ((t - 1 + h) % 3) * 8192;
      __builtin_amdgcn_s_setprio(1);
#pragma unroll
      for (int ct = 0; ct < 8; ct++) {
        int rowb = (ct * 32 + l31) * 32;
        int4v lo = *(const int4v*)(Vh + rowb + (0 ^ swzv));
        int4v hi = *(const int4v*)(Vh + rowb + (16 ^ swzv));
        o[ct] = mfma8s(pa, cat8(lo, hi), o[ct]);
      }
      __builtin_amdgcn_s_setprio(0);
    }

    __syncthreads();
  }

  // complete q-row sums (deferred cross-half reduce), then combine j-halves
  lsum += __shfl_xor(lsum, 32, 64);
  float* Lx = (float*)SMEM;   // 8 waves x 32 floats = 1 KB
  if (h == 0) Lx[w * 32 + l31] = lsum;
  __syncthreads();
  float ltot = lsum + Lx[((w ^ 4) * 32) + l31];
  float linv[16];
#pragma unroll
  for (int r = 0; r < 16; r++) linv[r] = 1.f / __shfl(ltot, drow(r, h), 64);
  __syncthreads();

  // O-exchange in two ct-halves (4 strips x 16 KB = 64 KB per round <= 80 KB)
  unsigned short* AOp = AO + (size_t)b * NN * CC;
  char* Rb = SMEM + p * 16384;
#pragma unroll
  for (int half = 0; half < 2; half++) {
    if (g == 1) {
#pragma unroll
      for (int c2 = 0; c2 < 4; c2++) {
        int ct = half * 4 + c2;
#pragma unroll
        for (int k = 0; k < 4; k++) {
          f32x4 v = {o[ct][4 * k], o[ct][4 * k + 1], o[ct][4 * k + 2], o[ct][4 * k + 3]};
          *(f32x4*)(Rb + ((c2 * 4 + k) * 64 + lane) * 16) = v;
        }
      }
    }
    __syncthreads();
    if (g == 0) {
#pragma unroll
      for (int c2 = 0; c2 < 4; c2++) {
        int ct = half * 4 + c2;
#pragma unroll
        for (int k = 0; k < 4; k++) {
          f32x4 qv = *(const f32x4*)(Rb + ((c2 * 4 + k) * 64 + lane) * 16);
#pragma unroll
          for (int j = 0; j < 4; j++) {
            int r = 4 * k + j;
            float v = (o[ct][r] + qv[j]) * linv[r];
            AOp[(size_t)(q0 + p * 32 + drow(r, h)) * CC + ct * 32 + l31] = f2bf(v);
          }
        }
      }
    }
    __syncthreads();
  }
}

// ---------------- K4: fused proj+conv + BN stats (swapped: lane-axis = channel) ----------------
__global__ __launch_bounds__(256, 1) void k_fused(const unsigned short* xt,
                                                  const unsigned short* AO,
                                                  const unsigned short* wc_b,
                                                  const unsigned short* wccN, const float* biasv,
                                                  unsigned short* yT, float* psum, float* psq) {
  __shared__ unsigned short XT[2][64 * 256], AL[2][64 * 256];   // 128 KB
  int o0 = blockIdx.x * 128;
  int tok_base = blockIdx.y * 256;
  int tid = threadIdx.x, lane = tid & 63, w = tid >> 6;
  int l31 = lane & 31, h = lane >> 5;
  int od = o0 + w * 32 + l31;

  short8 aw[32];
  const unsigned short* Wp1 = wc_b + (size_t)od * CC;
  const unsigned short* Wp2 = wccN + (size_t)od * CC;
#pragma unroll
  for (int kc = 0; kc < 16; kc++) {
    aw[kc] = *(const short8*)(Wp1 + kc * 16 + h * 8);
    aw[16 + kc] = *(const short8*)(Wp2 + kc * 16 + h * 8);
  }
  float bias_l = biasv[od];
  float sacc = 0.f, qacc = 0.f;

  const char* Xg = (const char*)xt;
  const char* Ag = (const char*)AO;
  stage64(Xg + (size_t)tok_base * 512, (char*)XT[0], tid);
  stage64(Ag + (size_t)tok_base * 512, (char*)AL[0], tid);
  __syncthreads();

  int cur = 0;
  for (int tt = 0; tt < 4; tt++) {
    if (tt < 3) {
      stage64(Xg + (size_t)(tok_base + (tt + 1) * 64) * 512, (char*)XT[cur ^ 1], tid);
      stage64(Ag + (size_t)(tok_base + (tt + 1) * 64) * 512, (char*)AL[cur ^ 1], tid);
    }
    const char* Xl = (const char*)XT[cur];
    const char* Al = (const char*)AL[cur];
    f32x16 acc[2];
#pragma unroll
    for (int t = 0; t < 2; t++)
#pragma unroll
      for (int r = 0; r < 16; r++) acc[t][r] = 0.f;
#pragma unroll
    for (int kc = 0; kc < 16; kc++) {
      acc[0] = mfma32(ldsfrag(Xl, l31, kc, h), aw[kc], acc[0]);
      acc[1] = mfma32(ldsfrag(Xl, 32 + l31, kc, h), aw[kc], acc[1]);
    }
#pragma unroll
    for (int kc = 0; kc < 16; kc++) {
      acc[0] = mfma32(ldsfrag(Al, l31, kc, h), aw[16 + kc], acc[0]);
      acc[1] = mfma32(ldsfrag(Al, 32 + l31, kc, h), aw[16 + kc], acc[1]);
    }
    int tok0 = tok_base + tt * 64;
#pragma unroll
    for (int t = 0; t < 2; t++)
#pragma unroll
      for (int r = 0; r < 16; r++) {
        float v = acc[t][r] + bias_l;
        sacc += v;
        qacc += v * v;
        int token = tok0 + t * 32 + drow(r, h);
        yT[(size_t)token * CC + od] = f2bf(v);
      }
    __syncthreads();
    cur ^= 1;
  }

  sacc += __shfl_xor(sacc, 32, 64);
  qacc += __shfl_xor(qacc, 32, 64);
  if (h == 0) {
    psum[blockIdx.y * 256 + od] = sacc;
    psq[blockIdx.y * 256 + od] = qacc;
  }
}

// ---------------- K5: finalize scale/shift (4-way parallel over 128 rows) ----------------
__global__ __launch_bounds__(1024) void k_stats2(const float* psum, const float* psq,
                                                 const float* gamma, const float* beta,
                                                 float* scale, float* shift) {
  __shared__ float S4[4][256], Q4[4][256];
  int o = threadIdx.x & 255, part = threadIdx.x >> 8;
  float S = 0.f, Q = 0.f;
  for (int b = part * 32; b < part * 32 + 32; b++) {
    S += psum[b * 256 + o];
    Q += psq[b * 256 + o];
  }
  S4[part][o] = S;
  Q4[part][o] = Q;
  __syncthreads();
  if (part == 0) {
    S = S4[0][o] + S4[1][o] + S4[2][o] + S4[3][o];
    Q = Q4[0][o] + Q4[1][o] + Q4[2][o] + Q4[3][o];
    const float inv = 1.f / (BB * NN);
    float mean = S * inv;
    float var = Q * inv - mean * mean;
    float rstd = rsqrtf(var + 1e-5f);
    float sc = gamma[o] * rstd;
    scale[o] = sc;
    shift[o] = beta[o] - mean * sc;
  }
}

// ---------------- K6: transpose yT + BN + relu + residual ----------------
__global__ __launch_bounds__(256) void k_final(const unsigned short* yT, const float* x,
                                               const float* scale, const float* shift, float* out) {
  __shared__ float tile[64][65];
  int n0 = blockIdx.x * 64, c0 = blockIdx.y * 64, b = blockIdx.z;
  int tid = threadIdx.x;
#pragma unroll
  for (int it = 0; it < 2; it++) {
    int rowl = (tid >> 3) + it * 32, slot = tid & 7;
    short8 v = *(const short8*)(yT + (size_t)(b * NN + n0 + rowl) * CC + c0 + slot * 8);
#pragma unroll
    for (int j = 0; j < 8; j++) tile[rowl][slot * 8 + j] = bf2f((unsigned short)v[j]);
  }
  __syncthreads();
  int nl = tid & 63, cg = tid >> 6;
  size_t xb = (size_t)b * CC * NN;
#pragma unroll
  for (int i = 0; i < 16; i++) {
    int cl = cg * 16 + i;
    int c = c0 + cl;
    float v = tile[nl][cl] * scale[c] + shift[c];
    size_t idx = xb + (size_t)c * NN + n0 + nl;
    out[idx] = x[idx] + fmaxf(v, 0.f);
  }
}

extern "C" void kernel_launch(void* const* d_in, const int* in_sizes, int n_in,
                              void* d_out, int out_size, void* d_ws, size_t ws_size,
                              hipStream_t stream) {
  const float* x      = (const float*)d_in[0];
  const float* w_qkv  = (const float*)d_in[1];
  const float* w_out  = (const float*)d_in[2];
  const float* b_out  = (const float*)d_in[3];
  const float* w_conv = (const float*)d_in[4];
  const float* b_conv = (const float*)d_in[5];
  const float* gamma  = (const float*)d_in[6];
  const float* beta   = (const float*)d_in[7];
  float* out = (float*)d_out;

  char* ws = (char*)d_ws;
  size_t off = 0;
  auto take = [&](size_t bytes) -> char* {
    char* p = ws + off;
    off += (bytes + 255) & ~(size_t)255;
    return p;
  };
  const size_t BNC  = (size_t)BB * NN * CC;
  unsigned char* Qf  = (unsigned char*)take(BNC);   // fp8; Qf+Kf reused as yT after attn
  unsigned char* Kf  = (unsigned char*)take(BNC);
  unsigned char* Vf  = (unsigned char*)take(BNC);
  unsigned short* xt = (unsigned short*)take(BNC * 2);
  unsigned short* AO = (unsigned short*)take(BNC * 2);
  unsigned short* wq_b = (unsigned short*)take((size_t)3 * CC * CC * 2);
  unsigned short* wc_b = (unsigned short*)take((size_t)CC * CC * 2);
  unsigned short* woT_b= (unsigned short*)take((size_t)CC * CC * 2);
  unsigned short* wccN = (unsigned short*)take((size_t)CC * CC * 2);
  float* biasv = (float*)take(CC * 4);
  float* psum  = (float*)take(128 * CC * 4);
  float* psq   = (float*)take(128 * CC * 4);
  float* scale = (float*)take(CC * 4);
  float* shift = (float*)take(CC * 4);
  unsigned short* yT = (unsigned short*)Qf;   // Qf+Kf region (16 MB) dead after k_attn

  k_prep<<<2896, 256, 0, stream>>>(w_qkv, w_conv, w_out, b_out, b_conv, x, wq_b, wc_b, woT_b,
                                   biasv, xt);
  k_wcc<<<dim3(2, 4), 256, 0, stream>>>(wc_b, woT_b, wccN);
  k_qkv<<<dim3(6, 128), 256, 0, stream>>>(xt, wq_b, Qf, Kf, Vf);
  k_attn<<<256, 512, 0, stream>>>(Qf, Kf, Vf, AO);
  k_fused<<<dim3(2, 128), 256, 0, stream>>>(xt, AO, wc_b, wccN, biasv, yT, psum, psq);
  k_stats2<<<1, 1024, 0, stream>>>(psum, psq, gamma, beta, scale, shift);
  k_final<<<dim3(32, 4, BB), 256, 0, stream>>>(yT, x, scale, shift, out);
}